// Round 2
// baseline (157.722 us; speedup 1.0000x reference)
//
#include <hip/hip_runtime.h>
#include <hip/hip_bf16.h>
#include <stdint.h>

#define B_DIM 32768
#define IN_DIM 512
#define OUT_DIM 512

typedef __bf16 bf16;
typedef bf16 bf16x8 __attribute__((ext_vector_type(8)));
typedef float f32x4 __attribute__((ext_vector_type(4)));

// ---- float-domain quantize+truncate ----
// reference: xi = int(v*2^sf) (trunc toward zero); keep top-4 significant bits
// of |xi|, restore sign. Equivalent in fp32 bits: truncf(v*2^sf), then mask
// mantissa to top 3 stored bits (3 stored + implicit = 4 significant bits).
// Sign-magnitude fp32 makes the magnitude-truncation automatic. The masked
// fp32's low 16 bits are zero, so bits>>16 IS the exact bf16.
__device__ __forceinline__ uint32_t quant2(float a, float b, float scale) {
    uint32_t ua = __float_as_uint(truncf(a * scale)) & 0xFFF00000u;
    uint32_t ub = __float_as_uint(truncf(b * scale)) & 0xFFF00000u;
    return (ua >> 16) | (ub & 0xFFFF0000u);   // packed bf16 pair (a low, b high)
}

__global__ void quant_kernel(const float* __restrict__ in, bf16* __restrict__ out,
                             int n4, const int* __restrict__ sf) {
    int i = blockIdx.x * blockDim.x + threadIdx.x;
    if (i >= n4) return;
    float scale = (float)(1 << *sf);
    float4 v = ((const float4*)in)[i];
    uint2 p;
    p.x = quant2(v.x, v.y, scale);
    p.y = quant2(v.z, v.w, scale);
    ((uint2*)out)[i] = p;
}

// ---- fused GEMM: C[m,n] = (sum_k q(x[m,k])*qw[n,k]) * 2^-(asf+wsf) + bias[n]
// x: [32768,512] fp32 (quantized on the fly), QW: [512,512] bf16 row-major.
// 128x128 block tile, BK=64, 4 waves 2x2, each wave 64x64 via 4x4 16x16x32 MFMA.
__global__ __launch_bounds__(256, 4)
void gemm_fused(const float* __restrict__ X, const bf16* __restrict__ QW,
                const float* __restrict__ bias, float* __restrict__ C,
                const int* __restrict__ wsf, const int* __restrict__ asf) {
    __shared__ bf16 As[128 * 64];
    __shared__ bf16 Bs[128 * 64];

    const int t    = threadIdx.x;
    const int w    = t >> 6;
    const int lane = t & 63;

    // XCD swizzle: 1024 blocks, 8 XCDs (blockIdx % 8). Give each XCD a band of
    // 32 M-tiles; the 4 N-tiles of one M-tile are adjacent slots on the SAME
    // XCD so A re-reads hit that XCD's L2.
    const int b    = blockIdx.x;
    const int xcd  = b & 7;
    const int slot = b >> 3;           // 0..127
    const int bm   = xcd * 32 + (slot >> 2);
    const int bn   = slot & 3;
    const int row0 = bm * 128;
    const int col0 = bn * 128;
    const int wm   = (w & 1) * 64;
    const int wn   = (w >> 1) * 64;

    const int ldr = t >> 3;            // 0..31: row within 32-row chunk
    const int ldc = (t & 7) * 8;       // element column (8 bf16 / 8 fp32 per thread)

    const float* Xbase = X  + (size_t)row0 * IN_DIM;
    const bf16*  Wbase = QW + (size_t)col0 * IN_DIM;

    const float ascale = (float)(1 << *asf);

    f32x4 acc[4][4];
    for (int mt = 0; mt < 4; ++mt)
        for (int nt = 0; nt < 4; ++nt)
            acc[mt][nt] = 0.0f;

    for (int k0 = 0; k0 < IN_DIM; k0 += 64) {
        // B staging first: async global->LDS (16B/lane), overlaps A quant work
        #pragma unroll
        for (int i = 0; i < 4; ++i) {
            const bf16* gb = Wbase + (size_t)(i * 32 + ldr) * IN_DIM + k0 + ldc;
            bf16*       lb = Bs + i * 2048 + w * 512;
            __builtin_amdgcn_global_load_lds((const __attribute__((address_space(1))) void*)gb,
                                             (__attribute__((address_space(3))) void*)lb, 16, 0, 0);
        }
        // A staging: fp32 load -> quant (4 ops/elem) -> ds_write_b128
        #pragma unroll
        for (int i = 0; i < 4; ++i) {
            const float* g = Xbase + (size_t)(i * 32 + ldr) * IN_DIM + k0 + ldc;
            float4 v0 = ((const float4*)g)[0];
            float4 v1 = ((const float4*)g)[1];
            uint4 p;
            p.x = quant2(v0.x, v0.y, ascale);
            p.y = quant2(v0.z, v0.w, ascale);
            p.z = quant2(v1.x, v1.y, ascale);
            p.w = quant2(v1.z, v1.w, ascale);
            *(uint4*)(As + (i * 32 + ldr) * 64 + ldc) = p;
        }
        __syncthreads();

        #pragma unroll
        for (int ks = 0; ks < 2; ++ks) {
            const int kcol = ks * 32 + (lane >> 4) * 8;
            const int arow = wm + (lane & 15);
            const int brow = wn + (lane & 15);
            bf16x8 af[4], bf[4];
            #pragma unroll
            for (int mt = 0; mt < 4; ++mt)
                af[mt] = *(const bf16x8*)(As + (arow + mt * 16) * 64 + kcol);
            #pragma unroll
            for (int nt = 0; nt < 4; ++nt)
                bf[nt] = *(const bf16x8*)(Bs + (brow + nt * 16) * 64 + kcol);
            #pragma unroll
            for (int mt = 0; mt < 4; ++mt)
                #pragma unroll
                for (int nt = 0; nt < 4; ++nt)
                    acc[mt][nt] = __builtin_amdgcn_mfma_f32_16x16x32_bf16(af[mt], bf[nt], acc[mt][nt], 0, 0, 0);
        }
        __syncthreads();
    }

    // epilogue: C/D layout col=lane&15, row=(lane>>4)*4+reg
    const float oscale = ldexpf(1.0f, -(*wsf + *asf));
    const int cl = lane & 15;
    const int rg = (lane >> 4) * 4;
    #pragma unroll
    for (int nt = 0; nt < 4; ++nt) {
        const int col = col0 + wn + nt * 16 + cl;
        const float bv = bias[col];
        #pragma unroll
        for (int mt = 0; mt < 4; ++mt) {
            f32x4 a = acc[mt][nt];
            #pragma unroll
            for (int r = 0; r < 4; ++r) {
                const int row = row0 + wm + mt * 16 + rg + r;
                C[(size_t)row * OUT_DIM + col] = a[r] * oscale + bv;
            }
        }
    }
}

extern "C" void kernel_launch(void* const* d_in, const int* in_sizes, int n_in,
                              void* d_out, int out_size, void* d_ws, size_t ws_size,
                              hipStream_t stream) {
    const float* x    = (const float*)d_in[0];
    const float* wgt  = (const float*)d_in[1];
    const float* bias = (const float*)d_in[2];
    const int*   wsf  = (const int*)d_in[3];
    const int*   asf  = (const int*)d_in[4];

    bf16* tw = (bf16*)d_ws;   // only weight needs pre-quantization (512 KB)

    const int nw4 = OUT_DIM * IN_DIM / 4;   // 65,536
    quant_kernel<<<(nw4 + 255) / 256, 256, 0, stream>>>(wgt, tw, nw4, wsf);

    const int grid = (B_DIM / 128) * (OUT_DIM / 128); // 1024
    gemm_fused<<<grid, 256, 0, stream>>>(x, tw, bias, (float*)d_out, wsf, asf);
}